// Round 6
// baseline (180.229 us; speedup 1.0000x reference)
//
#include <hip/hip_runtime.h>

// KMeans assignment: costs[i] = min_k ||x_i-c_k||^2, indices[i] = argmin_k.
// argmin over k of (c2[k] - 2*dot(x,c_k)); x2 additive, added at the end.
// Cross term via split-f16 3-pass MFMA (xh.ch + xl.ch + xh.cl), err ~1e-6.
// R6: SHIFTED PIPELINE -- body of chunk cc does: barrier / stage cc+1 /
// ds_read frags(cc) into reg-set[cc&1] / MFMA chunk cc-1 from the other set.
// MFMAs are independent of same-interval ds_reads -> LDS phase (~1152 cyc/CU)
// hides under MFMA phase (~1862 cyc/CU) instead of serializing with it.
// A stays in LDS (64 KB); Bh dbuf 16 KB -> 80 KB, 2 blocks/CU; Bl from L2.
// N=131072, D=128, K=1024.  d_out = [costs (N f32), indices-as-f32 (N)].

typedef _Float16 f16x8 __attribute__((ext_vector_type(8)));
typedef float    f32x4 __attribute__((ext_vector_type(4)));
typedef unsigned short u16;

constexpr int N = 131072, D = 128, K = 1024;
constexpr int MT = 128;   // points per block

union H2U { _Float16 h; unsigned short u; };

__device__ inline void gl_lds16(const void* g, void* l) {
  __builtin_amdgcn_global_load_lds(
      (const __attribute__((address_space(1))) unsigned int*)g,
      (__attribute__((address_space(3))) unsigned int*)l, 16, 0, 0);
}

// ---- prep: centers -> hi/lo f16 in fragment-major tiled layout + exact c2 ----
// ushort idx: (((cb*4 + kc)*4 + q)*128 + c%128)*8 + j, k = kc*32 + q*8 + j
__global__ void prep_centers(const float* __restrict__ centers,
                             u16* __restrict__ Bh, u16* __restrict__ Bl,
                             float* __restrict__ c2) {
  const int wave = threadIdx.x >> 6, lane = threadIdx.x & 63;
  const int c = blockIdx.x * 4 + wave;          // one wave per center
  const float2 v = ((const float2*)(centers + (size_t)c * D))[lane];
  float s = v.x * v.x + v.y * v.y;
  #pragma unroll
  for (int off = 32; off; off >>= 1) s += __shfl_xor(s, off, 64);
  if (lane == 0) c2[c] = s;

  H2U h0, h1, l0, l1;
  h0.h = (_Float16)v.x;  l0.h = (_Float16)(v.x - (float)h0.h);
  h1.h = (_Float16)v.y;  l1.h = (_Float16)(v.y - (float)h1.h);
  const int cb = c >> 7, cm = c & 127;
  const int kc = lane >> 4, q = (lane >> 2) & 3, j0 = (lane & 3) * 2;
  const size_t off = (((size_t)(cb * 4 + kc) * 4 + q) * 128 + cm) * 8 + j0;
  *(unsigned*)(Bh + off) = (unsigned)h0.u | ((unsigned)h1.u << 16);
  *(unsigned*)(Bl + off) = (unsigned)l0.u | ((unsigned)l1.u << 16);
}

// ---- main: 128 pts x 1024 centers per block; wave tile 64x64 (2x2 waves) ----
__global__ __launch_bounds__(256, 2) void kmeans_mfma(
    const float* __restrict__ x,
    const u16* __restrict__ Bh_g, const u16* __restrict__ Bl_g,
    const float* __restrict__ c2g,
    float* __restrict__ out_cost, float* __restrict__ out_idx)
{
  // 80 KB total: A [0,32768) u16, Bh dbuf [32768,40960) u16 (2 x 4096)
  __shared__ __align__(16) u16 smem[40960];
  u16* Ah = smem;            // [kc4][q4][m128][j8]  32 KB
  u16* Al = smem + 16384;    //                      32 KB

  const int tid = threadIdx.x;
  const int wave = tid >> 6, lane = tid & 63;
  const int wr = wave >> 1, wc = wave & 1;    // wave row/col in 2x2
  const int q = lane >> 4, ln = lane & 15;
  const int m0 = blockIdx.x * MT;

  // ---- stage A tile: fp32 -> (hi,lo) f16, tiled layout ----
  #pragma unroll
  for (int i = 0; i < 16; ++i) {
    const int flat = i * 256 + tid;            // 4096 float4s = 128x128 floats
    const int m = flat >> 5, c4 = flat & 31, k0 = c4 * 4;
    const float4 v = *(const float4*)(x + (size_t)(m0 + m) * D + k0);
    const int kc = k0 >> 5, qq = (k0 >> 3) & 3, j0 = k0 & 7;
    const float vv[4] = {v.x, v.y, v.z, v.w};
    H2U h[4], l[4];
    #pragma unroll
    for (int z = 0; z < 4; ++z) {
      h[z].h = (_Float16)vv[z];
      l[z].h = (_Float16)(vv[z] - (float)h[z].h);
    }
    const int off = ((kc * 4 + qq) * 128 + m) * 8 + j0;
    uint2 hp, lp;
    hp.x = h[0].u | ((unsigned)h[1].u << 16); hp.y = h[2].u | ((unsigned)h[3].u << 16);
    lp.x = l[0].u | ((unsigned)l[1].u << 16); lp.y = l[2].u | ((unsigned)l[3].u << 16);
    *(uint2*)(Ah + off) = hp;
    *(uint2*)(Al + off) = lp;
  }
  __syncthreads();

  // ---- x2 per point (thread tid<128 owns m=tid); A persists in LDS ----
  float x2m = 0.f;
  if (tid < MT) {
    #pragma unroll
    for (int kq = 0; kq < 16; ++kq) {
      const f16x8 hv = *(const f16x8*)(Ah + (kq * 128 + tid) * 8);
      const f16x8 lv = *(const f16x8*)(Al + (kq * 128 + tid) * 8);
      #pragma unroll
      for (int e = 0; e < 8; ++e) {
        const float xv = (float)hv[e] + (float)lv[e];
        x2m += xv * xv;
      }
    }
  }

  auto stageBh = [&](int cc, int p) {
    const size_t gbase = (size_t)cc * 4096;   // u16 per chunk (128c x 32k)
    u16* buf = smem + 32768 + p * 4096;
    #pragma unroll
    for (int i = 0; i < 2; ++i) {
      const size_t eoff = (size_t)i * 2048 + (size_t)wave * 512;  // wave-uniform
      gl_lds16(Bh_g + gbase + eoff + (size_t)lane * 8, buf + eoff);
    }
  };

  float bestV[16]; int bestI[16];
  #pragma unroll
  for (int b = 0; b < 16; ++b) { bestV[b] = 3.4e38f; bestI[b] = 0; }

  f32x4 acc[4][4];
  #pragma unroll
  for (int mt = 0; mt < 4; ++mt)
    #pragma unroll
    for (int nt = 0; nt < 4; ++nt)
      acc[mt][nt] = (f32x4){0.f, 0.f, 0.f, 0.f};

  f16x8 ah[4], al[4];       // A frags of the most recently read chunk
  f16x8 bhS[2][4], blS[2][4];  // B frag sets, parity = chunk & 1

#define READ_B(J, CC)  do {                                                    \
    const u16* buf_ = smem + 32768 + ((J) & 1) * 4096;                         \
    _Pragma("unroll")                                                          \
    for (int t = 0; t < 4; ++t) {                                              \
      bhS[(J) & 1][t] =                                                        \
          *(const f16x8*)(buf_ + (q * 128 + wc * 64 + t * 16 + ln) * 8);       \
      blS[(J) & 1][t] = *(const f16x8*)(Bl_g +                                 \
          ((size_t)((CC) * 4 + q) * 128 + wc * 64 + t * 16 + ln) * 8);         \
    }                                                                          \
  } while (0)

#define READ_A(KC)  do {                                                       \
    _Pragma("unroll")                                                          \
    for (int t = 0; t < 4; ++t) {                                              \
      const int aoff_ = (((KC) * 4 + q) * 128 + wr * 64 + t * 16 + ln) * 8;    \
      ah[t] = *(const f16x8*)(Ah + aoff_);                                     \
      al[t] = *(const f16x8*)(Al + aoff_);                                     \
    }                                                                          \
  } while (0)

#define MFMA_GROUP(MS)  do {                                                   \
    _Pragma("unroll")                                                          \
    for (int mt = 0; mt < 4; ++mt)                                             \
      _Pragma("unroll")                                                        \
      for (int nt = 0; nt < 4; ++nt)                                           \
        acc[mt][nt] = __builtin_amdgcn_mfma_f32_16x16x32_f16(                  \
            ah[mt], bhS[MS][nt], acc[mt][nt], 0, 0, 0);                        \
    _Pragma("unroll")                                                          \
    for (int mt = 0; mt < 4; ++mt)                                             \
      _Pragma("unroll")                                                        \
      for (int nt = 0; nt < 4; ++nt)                                           \
        acc[mt][nt] = __builtin_amdgcn_mfma_f32_16x16x32_f16(                  \
            al[mt], bhS[MS][nt], acc[mt][nt], 0, 0, 0);                        \
    _Pragma("unroll")                                                          \
    for (int mt = 0; mt < 4; ++mt)                                             \
      _Pragma("unroll")                                                        \
      for (int nt = 0; nt < 4; ++nt)                                           \
        acc[mt][nt] = __builtin_amdgcn_mfma_f32_16x16x32_f16(                  \
            ah[mt], blS[MS][nt], acc[mt][nt], 0, 0, 0);                        \
  } while (0)

#define EPILOGUE(G)  do {                                                      \
    _Pragma("unroll")                                                          \
    for (int nt = 0; nt < 4; ++nt) {                                           \
      const int n_ = (G) * 128 + wc * 64 + nt * 16 + ln;                       \
      const float c2v_ = c2g[n_];                                              \
      _Pragma("unroll")                                                        \
      for (int mt = 0; mt < 4; ++mt)                                           \
        _Pragma("unroll")                                                      \
        for (int r = 0; r < 4; ++r) {                                          \
          const float s_ = __builtin_fmaf(-2.f, acc[mt][nt][r], c2v_);         \
          const int b_ = mt * 4 + r;                                           \
          if (s_ < bestV[b_]) { bestV[b_] = s_; bestI[b_] = n_; }              \
        }                                                                      \
    }                                                                          \
    _Pragma("unroll")                                                          \
    for (int mt = 0; mt < 4; ++mt)                                             \
      _Pragma("unroll")                                                        \
      for (int nt = 0; nt < 4; ++nt)                                           \
        acc[mt][nt] = (f32x4){0.f, 0.f, 0.f, 0.f};                             \
  } while (0)

  stageBh(0, 0);

  for (int it = 0; it < 8; ++it) {
    const int c0 = it * 4;
    // sub-body 0: read chunk c0 (set0); MFMA chunk c0-1 (set1); epi group it-1
    __syncthreads();
    stageBh(c0 + 1, 1);
    READ_B(0, c0);
    if (it > 0) { MFMA_GROUP(1); EPILOGUE(it - 1); }
    READ_A(0);
    // sub-body 1: read c0+1 (set1); MFMA c0 (set0)
    __syncthreads();
    stageBh(c0 + 2, 0);
    READ_B(1, c0 + 1);
    MFMA_GROUP(0);
    READ_A(1);
    // sub-body 2: read c0+2 (set0); MFMA c0+1 (set1)
    __syncthreads();
    stageBh(c0 + 3, 1);
    READ_B(0, c0 + 2);
    MFMA_GROUP(1);
    READ_A(2);
    // sub-body 3: read c0+3 (set1); MFMA c0+2 (set0)
    __syncthreads();
    if (it < 7) stageBh(c0 + 4, 0);
    READ_B(1, c0 + 3);
    MFMA_GROUP(0);
    READ_A(3);
  }
  // drain: MFMA chunk 31 (set1), epilogue group 7
  MFMA_GROUP(1);
  EPILOGUE(7);

#undef READ_B
#undef READ_A
#undef MFMA_GROUP
#undef EPILOGUE

  // ---- reduce across the 16 lanes (ln) sharing the same m rows ----
  #pragma unroll
  for (int b = 0; b < 16; ++b) {
    float v = bestV[b]; int idx = bestI[b];
    #pragma unroll
    for (int off = 1; off < 16; off <<= 1) {
      const float ov = __shfl_xor(v, off, 64);
      const int   oi = __shfl_xor(idx, off, 64);
      if (ov < v || (ov == v && oi < idx)) { v = ov; idx = oi; }
    }
    bestV[b] = v; bestI[b] = idx;
  }

  __syncthreads();                       // all buffer reads done -> overlay
  float* redV = (float*)(smem + 32768);  // 1 KB
  int*   redI = (int*)(smem + 33280);    // 1 KB
  if (ln == 0) {
    #pragma unroll
    for (int b = 0; b < 16; ++b) {
      const int ml = wr * 64 + (b >> 2) * 16 + q * 4 + (b & 3);
      redV[ml * 2 + wc] = bestV[b];
      redI[ml * 2 + wc] = bestI[b];
    }
  }
  __syncthreads();
  if (tid < MT) {
    float v = redV[tid * 2]; int idx = redI[tid * 2];
    const float v1 = redV[tid * 2 + 1]; const int i1 = redI[tid * 2 + 1];
    if (v1 < v || (v1 == v && i1 < idx)) { v = v1; idx = i1; }
    float cost = x2m + v;
    if (cost < 0.f) cost = 0.f;          // clamp like reference
    out_cost[m0 + tid] = cost;
    out_idx[m0 + tid]  = (float)idx;
  }
}

extern "C" void kernel_launch(void* const* d_in, const int* in_sizes, int n_in,
                              void* d_out, int out_size, void* d_ws, size_t ws_size,
                              hipStream_t stream) {
  const float* x       = (const float*)d_in[0];
  const float* centers = (const float*)d_in[1];
  u16*   Bh = (u16*)d_ws;                    // 256 KB
  u16*   Bl = Bh + (size_t)K * D;            // 256 KB
  float* c2 = (float*)(Bl + (size_t)K * D);  // 4 KB
  float* out_cost = (float*)d_out;
  float* out_idx  = out_cost + N;

  prep_centers<<<K / 4, 256, 0, stream>>>(centers, Bh, Bl, c2);
  kmeans_mfma<<<N / MT, 256, 0, stream>>>(x, Bh, Bl, c2, out_cost, out_idx);
}